// Round 1
// baseline (143.380 us; speedup 1.0000x reference)
//
#include <hip/hip_runtime.h>
#include <hip/hip_bf16.h>

#define RANK    16
#define D_IN    2048
#define D_OUT   2048
#define N_TOK   1024
#define N_BATCH 8
#define TPB     16           // tokens per block
#define SCALING 1.0f         // ALPHA/RANK = 16/16

__device__ __forceinline__ float dot4(float4 a, float4 b) {
    return a.x * b.x + a.y * b.y + a.z * b.z + a.w * b.w;
}

__global__ __launch_bounds__(256, 2)
void lora_fused(const float* __restrict__ x,
                const float* __restrict__ A,
                const float* __restrict__ B,
                const int* __restrict__ ids,
                float* __restrict__ out) {
    __shared__ __align__(16) float Bt[RANK][512];   // 32 KB B tile
    __shared__ __align__(16) float bx[TPB][RANK];   // 1 KB Bx results

    const int b    = blockIdx.y;
    const int tok0 = blockIdx.x * TPB;
    const int aid  = ids[b];
    const int tid  = threadIdx.x;
    const int wave = tid >> 6;
    const int lane = tid & 63;

    const float* __restrict__ xb = x + ((size_t)b * N_TOK + tok0) * D_IN;
    const float* __restrict__ Ba = B + (size_t)aid * RANK * D_IN;
    const float* __restrict__ Aa = A + (size_t)aid * D_OUT * RANK;
    float* __restrict__ ob = out + ((size_t)b * N_TOK + tok0) * D_OUT;

    // ---------------- Step 1: Bx[t][r] = sum_i x[t,i] * B[a,r,i] ----------------
    // wave handles tokens [wave*4, wave*4+4); lanes cover i (float4, coalesced)
    float acc[4][RANK];
    #pragma unroll
    for (int t = 0; t < 4; ++t)
        #pragma unroll
        for (int r = 0; r < RANK; ++r) acc[t][r] = 0.f;

    for (int tile = 0; tile < 4; ++tile) {
        __syncthreads();   // protect previous tile's consumers
        // stage B[a][0..15][tile*512 .. +512) : 8192 floats, 8 float4 per thread
        #pragma unroll
        for (int k = 0; k < 8; ++k) {
            int flat = (k * 256 + tid) * 4;      // 0..8188
            int r = flat >> 9;                   // /512
            int c = flat & 511;
            *reinterpret_cast<float4*>(&Bt[r][c]) =
                *reinterpret_cast<const float4*>(&Ba[r * D_IN + tile * 512 + c]);
        }
        __syncthreads();

        #pragma unroll
        for (int t = 0; t < 4; ++t) {
            const float* xr = xb + (size_t)(wave * 4 + t) * D_IN + tile * 512;
            #pragma unroll
            for (int it = 0; it < 2; ++it) {
                int il = it * 256 + lane * 4;
                float4 xv = *reinterpret_cast<const float4*>(&xr[il]);
                #pragma unroll
                for (int r = 0; r < RANK; ++r) {
                    float4 bv = *reinterpret_cast<const float4*>(&Bt[r][il]);
                    acc[t][r] += dot4(xv, bv);
                }
            }
        }
    }

    // butterfly-reduce each acc[t][r] across the 64 lanes
    #pragma unroll
    for (int t = 0; t < 4; ++t) {
        #pragma unroll
        for (int r = 0; r < RANK; ++r) {
            float v = acc[t][r];
            #pragma unroll
            for (int off = 32; off > 0; off >>= 1)
                v += __shfl_xor(v, off, 64);
            acc[t][r] = v;  // every lane now holds the full sum
        }
        if (lane == 0) {
            int tt = wave * 4 + t;
            *reinterpret_cast<float4*>(&bx[tt][0])  = make_float4(acc[t][0],  acc[t][1],  acc[t][2],  acc[t][3]);
            *reinterpret_cast<float4*>(&bx[tt][4])  = make_float4(acc[t][4],  acc[t][5],  acc[t][6],  acc[t][7]);
            *reinterpret_cast<float4*>(&bx[tt][8])  = make_float4(acc[t][8],  acc[t][9],  acc[t][10], acc[t][11]);
            *reinterpret_cast<float4*>(&bx[tt][12]) = make_float4(acc[t][12], acc[t][13], acc[t][14], acc[t][15]);
        }
    }
    __syncthreads();

    // ---------------- Step 2: out[t][o] = sum_r Bx[t][r] * A[a,o,r] ----------------
    // wave covers o in [wave*512, wave*512+512); A cached in regs, reused over 16 tokens
    #pragma unroll
    for (int it = 0; it < 2; ++it) {
        int o0 = wave * 512 + it * 256 + lane * 4;
        float4 Ar[4][4];
        #pragma unroll
        for (int oo = 0; oo < 4; ++oo)
            #pragma unroll
            for (int q = 0; q < 4; ++q)
                Ar[oo][q] = *reinterpret_cast<const float4*>(&Aa[(size_t)(o0 + oo) * RANK + q * 4]);

        #pragma unroll
        for (int t = 0; t < TPB; ++t) {
            float4 b0 = *reinterpret_cast<const float4*>(&bx[t][0]);   // broadcast reads
            float4 b1 = *reinterpret_cast<const float4*>(&bx[t][4]);
            float4 b2 = *reinterpret_cast<const float4*>(&bx[t][8]);
            float4 b3 = *reinterpret_cast<const float4*>(&bx[t][12]);
            float4 res;
            res.x = dot4(Ar[0][0], b0) + dot4(Ar[0][1], b1) + dot4(Ar[0][2], b2) + dot4(Ar[0][3], b3);
            res.y = dot4(Ar[1][0], b0) + dot4(Ar[1][1], b1) + dot4(Ar[1][2], b2) + dot4(Ar[1][3], b3);
            res.z = dot4(Ar[2][0], b0) + dot4(Ar[2][1], b1) + dot4(Ar[2][2], b2) + dot4(Ar[2][3], b3);
            res.w = dot4(Ar[3][0], b0) + dot4(Ar[3][1], b1) + dot4(Ar[3][2], b2) + dot4(Ar[3][3], b3);
            res.x *= SCALING; res.y *= SCALING; res.z *= SCALING; res.w *= SCALING;
            *reinterpret_cast<float4*>(&ob[(size_t)t * D_OUT + o0]) = res;
        }
    }
}

extern "C" void kernel_launch(void* const* d_in, const int* in_sizes, int n_in,
                              void* d_out, int out_size, void* d_ws, size_t ws_size,
                              hipStream_t stream) {
    const float* x   = (const float*)d_in[0];
    const float* A   = (const float*)d_in[1];
    const float* B   = (const float*)d_in[2];
    const int*   ids = (const int*)d_in[3];
    float* out = (float*)d_out;

    dim3 grid(N_TOK / TPB, N_BATCH);   // (64, 8) = 512 blocks
    lora_fused<<<grid, 256, 0, stream>>>(x, A, B, ids, out);
}